// Round 5
// baseline (150.167 us; speedup 1.0000x reference)
//
#include <hip/hip_runtime.h>
#include <math.h>

typedef __attribute__((ext_vector_type(8))) short short8;
typedef __attribute__((ext_vector_type(4))) float f32x4;
typedef __attribute__((ext_vector_type(4))) unsigned int u32x4;
typedef __attribute__((ext_vector_type(2))) unsigned long long u64x2;

static __device__ __forceinline__ unsigned int fbits(float f) {
    union { float f; unsigned int u; } v; v.f = f; return v.u;
}
// pack two f32 -> bf16 pair in ONE v_perm_b32: {lo16: bf16(lo), hi16: bf16(hi)}
static __device__ __forceinline__ unsigned int pk(float lo, float hi) {
    return __builtin_amdgcn_perm(fbits(hi), fbits(lo), 0x07060302u);
}
static __device__ __forceinline__ float leaky(float x) { return fmaxf(x, 0.01f * x); }

static __device__ __forceinline__ f32x4 mm(short8 a, short8 b, f32x4 c) {
    return __builtin_amdgcn_mfma_f32_16x16x32_bf16(a, b, c, 0, 0, 0);
}

// LDS: row stride 18 u32. u32 cell (row, c) = bf16 pair (k=c, k=c+16) of that
// row's activation vector. Simultaneously MFMA A-layout (lane(i15,q) reads u64s
// {2q, 2q+1} of row i15) and the natural pack target from MFMA C-layout
// (lane(i15,q) writes rows 4q+r at col i15). k-permutation applied identically
// to B fragments so the MFMA dot product is consistent (validated in R3).
// __syncthreads() at every phase boundary: the pack-writes (u32) and next-layer
// A-loads (u64) overlap in address but differ in type — without the barrier's
// compiler-level fence, TBAA reorders them (R4's NaN failure).

__global__ __launch_bounds__(256, 4) void aero_mfma4(
    const float* __restrict__ vin, const float* __restrict__ win,
    const float* __restrict__ gW1, const float* __restrict__ gb1,
    const float* __restrict__ gW2, const float* __restrict__ gb2,
    const float* __restrict__ gWd1, const float* __restrict__ gbd1,
    const float* __restrict__ gWd2, const float* __restrict__ gbd2,
    const float* __restrict__ gbias,
    float* __restrict__ out, int nrows)
{
    __shared__ unsigned int hb32[256 * 18];
    unsigned long long* const hb64 = (unsigned long long*)hb32;
    float* const hbf = (float*)hb32;

    const int tid  = threadIdx.x;
    const int i15  = tid & 15;
    const int q    = (tid >> 4) & 3;
    const int wbase = tid & 192;          // wave-private 64-row LDS window
    int row = blockIdx.x * 256 + tid;
    if (row >= nrows) row = nrows - 1;    // uniform control flow for barriers

    // -------- weight B-fragments (per-lane VMEM; L2-resident) --------
    const int n0 = i15, n1 = i15 + 16;
    unsigned int w2a[4], w2b[4], w3a[4], w3b[4];
    {
        const float* p;
        f32x4 lo, hi;
        p = gW2 + n0 * 32 + 4 * q;  lo = *(const f32x4*)p; hi = *(const f32x4*)(p + 16);
        w2a[0] = pk(lo.x, hi.x); w2a[1] = pk(lo.y, hi.y); w2a[2] = pk(lo.z, hi.z); w2a[3] = pk(lo.w, hi.w);
        p = gW2 + n1 * 32 + 4 * q;  lo = *(const f32x4*)p; hi = *(const f32x4*)(p + 16);
        w2b[0] = pk(lo.x, hi.x); w2b[1] = pk(lo.y, hi.y); w2b[2] = pk(lo.z, hi.z); w2b[3] = pk(lo.w, hi.w);
        p = gWd1 + n0 * 32 + 4 * q; lo = *(const f32x4*)p; hi = *(const f32x4*)(p + 16);
        w3a[0] = pk(lo.x, hi.x); w3a[1] = pk(lo.y, hi.y); w3a[2] = pk(lo.z, hi.z); w3a[3] = pk(lo.w, hi.w);
        p = gWd1 + n1 * 32 + 4 * q; lo = *(const f32x4*)p; hi = *(const f32x4*)(p + 16);
        w3b[0] = pk(lo.x, hi.x); w3b[1] = pk(lo.y, hi.y); w3b[2] = pk(lo.z, hi.z); w3b[3] = pk(lo.w, hi.w);
    }
    // W1 (3->32): only quad 0, lo halves, k<3 nonzero
    unsigned int w1a[4] = {0, 0, 0, 0}, w1b[4] = {0, 0, 0, 0};
    if (q == 0) {
        const float* pa = gW1 + n0 * 3;
        const float* pb = gW1 + n1 * 3;
        w1a[0] = fbits(pa[0]) >> 16; w1a[1] = fbits(pa[1]) >> 16; w1a[2] = fbits(pa[2]) >> 16;
        w1b[0] = fbits(pb[0]) >> 16; w1b[1] = fbits(pb[1]) >> 16; w1b[2] = fbits(pb[2]) >> 16;
    }
    // Wd2 (32->3): N=3, only lanes i15<3 carry B
    unsigned int w4[4] = {0, 0, 0, 0};
    float b4 = 0.0f;
    if (i15 < 3) {
        const float* p = gWd2 + i15 * 32 + 4 * q;
        const f32x4 lo = *(const f32x4*)p;
        const f32x4 hi = *(const f32x4*)(p + 16);
        w4[0] = pk(lo.x, hi.x); w4[1] = pk(lo.y, hi.y); w4[2] = pk(lo.z, hi.z); w4[3] = pk(lo.w, hi.w);
        b4 = gbd2[i15];
    }
    const float b1a = gb1[n0],  b1b = gb1[n1];
    const float b2a = gb2[n0],  b2b = gb2[n1];
    const float b3a = gbd1[n0], b3b = gbd1[n1];

    const short8 B1a = __builtin_bit_cast(short8, (u32x4){w1a[0], w1a[1], w1a[2], w1a[3]});
    const short8 B1b = __builtin_bit_cast(short8, (u32x4){w1b[0], w1b[1], w1b[2], w1b[3]});
    const short8 B2a = __builtin_bit_cast(short8, (u32x4){w2a[0], w2a[1], w2a[2], w2a[3]});
    const short8 B2b = __builtin_bit_cast(short8, (u32x4){w2b[0], w2b[1], w2b[2], w2b[3]});
    const short8 B3a = __builtin_bit_cast(short8, (u32x4){w3a[0], w3a[1], w3a[2], w3a[3]});
    const short8 B3b = __builtin_bit_cast(short8, (u32x4){w3b[0], w3b[1], w3b[2], w3b[3]});
    const short8 B4  = __builtin_bit_cast(short8, (u32x4){w4[0],  w4[1],  w4[2],  w4[3]});

    // -------- Gram-Schmidt (lane = row) --------
    const float v0 = vin[3 * row + 0], v1 = vin[3 * row + 1], v2 = vin[3 * row + 2];
    const float w0 = win[3 * row + 0], w1 = win[3 * row + 1], w2 = win[3 * row + 2];

    const float nv  = sqrtf(v0 * v0 + v1 * v1 + v2 * v2) + 1e-8f;
    const float rnv = 1.0f / nv;
    const float a0 = v0 * rnv, a1 = v1 * rnv, a2 = v2 * rnv;       // v_on
    const float proj = w0 * a0 + w1 * a1 + w2 * a2;
    const float o0 = w0 - proj * a0, o1 = w1 - proj * a1, o2 = w2 - proj * a2;
    const float nw  = sqrtf(o0 * o0 + o1 * o1 + o2 * o2) + 1e-8f;
    const float rnw = 1.0f / nw;
    const float c0 = o0 * rnw, c1 = o1 * rnw, c2 = o2 * rnw;       // w_on
    const float u0 = a1 * c2 - a2 * c1;                            // u_on
    const float u1 = a2 * c0 - a0 * c2;
    const float u2 = a0 * c1 - a1 * c0;

    const float f0 = v0 * a0 + v1 * a1 + v2 * a2;
    const float f1 = proj;
    const float f2 = w0 * c0 + w1 * c1 + w2 * c2;

    // feat -> LDS in A-layout (k=0..2 lo halves of u32 cols 0..2; col 3 = 0)
    hb64[tid * 9 + 0] = (unsigned long long)(fbits(f0) >> 16)
                      | ((unsigned long long)(fbits(f1) >> 16) << 32);
    hb64[tid * 9 + 1] = (unsigned long long)(fbits(f2) >> 16);
    __syncthreads();

    // -------- layer 1 MFMA: h1 = leaky(feat @ W1^T + b1), kept in C-layout ----
    float h1c[4][8];   // [m-tile][ntile0 r0..3 | ntile1 r0..3]
    #pragma unroll
    for (int t = 0; t < 4; ++t) {
        const int ra = (wbase + 16 * t + i15) * 9;
        u64x2 av;
        av.x = (q == 0) ? hb64[ra + 0] : 0ull;
        av.y = (q == 0) ? hb64[ra + 1] : 0ull;
        const short8 af = __builtin_bit_cast(short8, av);
        f32x4 acc0 = {b1a, b1a, b1a, b1a};
        f32x4 acc1 = {b1b, b1b, b1b, b1b};
        acc0 = mm(af, B1a, acc0);
        acc1 = mm(af, B1b, acc1);
        #pragma unroll
        for (int r = 0; r < 4; ++r) {
            h1c[t][r]     = leaky(acc0[r]);
            h1c[t][4 + r] = leaky(acc1[r]);
        }
    }
    __syncthreads();
    // pack h1 C-layout -> LDS A-layout
    #pragma unroll
    for (int t = 0; t < 4; ++t) {
        const int zr = (wbase + 16 * t + 4 * q) * 18 + i15;
        #pragma unroll
        for (int r = 0; r < 4; ++r)
            hb32[zr + 18 * r] = pk(h1c[t][r], h1c[t][4 + r]);
    }
    __syncthreads();

    // -------- layer 2 MFMA + gate: h2 = leaky(h1 @ W2^T + b2) * h1 ----------
    #pragma unroll
    for (int t = 0; t < 4; ++t) {
        const int ra = (wbase + 16 * t + i15) * 9 + 2 * q;
        u64x2 av; av.x = hb64[ra]; av.y = hb64[ra + 1];
        const short8 af = __builtin_bit_cast(short8, av);
        f32x4 acc0 = {b2a, b2a, b2a, b2a};
        f32x4 acc1 = {b2b, b2b, b2b, b2b};
        acc0 = mm(af, B2a, acc0);
        acc1 = mm(af, B2b, acc1);
        #pragma unroll
        for (int r = 0; r < 4; ++r) {
            const float g0 = leaky(acc0[r]) * h1c[t][r];        // same (row,col) cell
            const float g1 = leaky(acc1[r]) * h1c[t][4 + r];
            h1c[t][r] = g0;                                      // reuse as staging
            h1c[t][4 + r] = g1;
        }
    }
    __syncthreads();
    #pragma unroll
    for (int t = 0; t < 4; ++t) {
        const int zr = (wbase + 16 * t + 4 * q) * 18 + i15;
        #pragma unroll
        for (int r = 0; r < 4; ++r)
            hb32[zr + 18 * r] = pk(h1c[t][r], h1c[t][4 + r]);
    }
    __syncthreads();

    // -------- layer 3 MFMA: h3 = leaky(h2 @ Wd1^T + bd1) ----------
    #pragma unroll
    for (int t = 0; t < 4; ++t) {
        const int ra = (wbase + 16 * t + i15) * 9 + 2 * q;
        u64x2 av; av.x = hb64[ra]; av.y = hb64[ra + 1];
        const short8 af = __builtin_bit_cast(short8, av);
        f32x4 acc0 = {b3a, b3a, b3a, b3a};
        f32x4 acc1 = {b3b, b3b, b3b, b3b};
        acc0 = mm(af, B3a, acc0);
        acc1 = mm(af, B3b, acc1);
        #pragma unroll
        for (int r = 0; r < 4; ++r) {
            h1c[t][r]     = leaky(acc0[r]);
            h1c[t][4 + r] = leaky(acc1[r]);
        }
    }
    __syncthreads();
    #pragma unroll
    for (int t = 0; t < 4; ++t) {
        const int zr = (wbase + 16 * t + 4 * q) * 18 + i15;
        #pragma unroll
        for (int r = 0; r < 4; ++r)
            hb32[zr + 18 * r] = pk(h1c[t][r], h1c[t][4 + r]);
    }
    __syncthreads();

    // -------- layer 4 MFMA (32->3): y in C-layout cols 0..2, written as f32 ----
    #pragma unroll
    for (int t = 0; t < 4; ++t) {
        const int ra = (wbase + 16 * t + i15) * 9 + 2 * q;
        u64x2 av; av.x = hb64[ra]; av.y = hb64[ra + 1];
        const short8 af = __builtin_bit_cast(short8, av);
        f32x4 acc = {b4, b4, b4, b4};
        acc = mm(af, B4, acc);
        if (i15 < 3) {
            const int zr = (wbase + 16 * t + 4 * q) * 18 + i15;
            #pragma unroll
            for (int r = 0; r < 4; ++r)
                hbf[zr + 18 * r] = acc[r];
        }
    }
    __syncthreads();

    // -------- epilogue (lane = row): rotate + bias + store --------
    const float y0 = hbf[tid * 18 + 0];
    const float y1 = hbf[tid * 18 + 1];
    const float y2 = hbf[tid * 18 + 2];
    out[3 * row + 0] = fmaf(a0, y0, fmaf(c0, y1, fmaf(u0, y2, gbias[0])));
    out[3 * row + 1] = fmaf(a1, y0, fmaf(c1, y1, fmaf(u1, y2, gbias[1])));
    out[3 * row + 2] = fmaf(a2, y0, fmaf(c2, y1, fmaf(u2, y2, gbias[2])));
}

extern "C" void kernel_launch(void* const* d_in, const int* in_sizes, int n_in,
                              void* d_out, int out_size, void* d_ws, size_t ws_size,
                              hipStream_t stream) {
    const float* v    = (const float*)d_in[0];
    const float* w    = (const float*)d_in[1];
    const float* W1   = (const float*)d_in[2];
    const float* b1   = (const float*)d_in[3];
    const float* W2   = (const float*)d_in[4];
    const float* b2   = (const float*)d_in[5];
    const float* Wd1  = (const float*)d_in[6];
    const float* bd1  = (const float*)d_in[7];
    const float* Wd2  = (const float*)d_in[8];
    const float* bd2  = (const float*)d_in[9];
    const float* bias = (const float*)d_in[10];

    const int nrows = in_sizes[0] / 3;
    dim3 block(256);
    dim3 grid((nrows + 255) / 256);
    hipLaunchKernelGGL(aero_mfma4, grid, block, 0, stream,
                       v, w, W1, b1, W2, b2, Wd1, bd1, Wd2, bd2, bias,
                       (float*)d_out, nrows);
}